// Round 2
// baseline (276.859 us; speedup 1.0000x reference)
//
#include <hip/hip_runtime.h>
#include <stdint.h>

typedef unsigned short u16;
typedef __bf16 bf16x8 __attribute__((ext_vector_type(8)));
typedef float f32x4 __attribute__((ext_vector_type(4)));

#define M_ROWS 16384
#define K_DIM  1568
#define H_DIM  128
#define NQ     384           // q,k,v concatenated
#define BK     32
#define LSTR   40            // LDS row stride in bf16 elems (32 + 8 pad)

__device__ __forceinline__ u16 f32_to_bf16_rne(float f) {
    uint32_t u = __float_as_uint(f);
    uint32_t r = (u + 0x7FFFu + ((u >> 16) & 1u)) >> 16;
    return (u16)r;
}

// ---------------------------------------------------------------------------
// Kernel 1: transpose + bf16-convert the three [K,H] f32 weights into
// WT[3][H][K] (bf16 bits)
// ---------------------------------------------------------------------------
__global__ __launch_bounds__(256) void wtrans_kernel(
    const float* __restrict__ wq, const float* __restrict__ wk,
    const float* __restrict__ wv, u16* __restrict__ wt)
{
    const float* w = (blockIdx.y == 0) ? wq : (blockIdx.y == 1) ? wk : wv;
    int idx = blockIdx.x * 256 + threadIdx.x;      // over H*K = 200704 (exact)
    int n = idx / K_DIM;
    int k = idx - n * K_DIM;
    wt[(size_t)blockIdx.y * H_DIM * K_DIM + idx] =
        f32_to_bf16_rne(w[(size_t)k * H_DIM + n]);
}

// ---------------------------------------------------------------------------
// Kernel 2: qkv[M][384] fp32 = x[M][K] @ [wq|wk|wv]   (bf16 MFMA)
// grid (M/128, 3); block 256 = 4 waves, each wave 64x64 (4x4 of 16x16x32)
// x is fp32 -> converted to bf16 while staging into LDS.
// ---------------------------------------------------------------------------
__global__ __launch_bounds__(256) void qkv_gemm_kernel(
    const float* __restrict__ x,     // [M,K] fp32
    const u16* __restrict__ wt,      // [3][H][K] bf16 bits (transposed)
    float* __restrict__ qkv)         // [M,384] fp32
{
    __shared__ u16 As[128 * LSTR];
    __shared__ u16 Bs[128 * LSTR];

    const int tid  = threadIdx.x;
    const int m0   = blockIdx.x * 128;
    const int wsel = blockIdx.y;
    const u16* wtb = wt + (size_t)wsel * H_DIM * K_DIM;

    const int lane = tid & 63;
    const int wave = tid >> 6;
    const int wm   = (wave & 1) * 64;
    const int wn   = (wave >> 1) * 64;
    const int lrow = lane & 15;
    const int kbase = (lane >> 4) * 8;

    f32x4 acc[4][4] = {};

    for (int k0 = 0; k0 < K_DIM; k0 += BK) {
        // stage A tile: 128 rows x 32 k; f32 -> bf16 convert (512 chunks of 8)
        #pragma unroll
        for (int c = tid; c < 512; c += 256) {
            int row = c >> 2;
            int ko  = (c & 3) << 3;
            const float* src = x + (size_t)(m0 + row) * K_DIM + k0 + ko;
            float4 f0 = *(const float4*)(src);
            float4 f1 = *(const float4*)(src + 4);
            uint4 v;
            v.x = f32_to_bf16_rne(f0.x) | ((uint32_t)f32_to_bf16_rne(f0.y) << 16);
            v.y = f32_to_bf16_rne(f0.z) | ((uint32_t)f32_to_bf16_rne(f0.w) << 16);
            v.z = f32_to_bf16_rne(f1.x) | ((uint32_t)f32_to_bf16_rne(f1.y) << 16);
            v.w = f32_to_bf16_rne(f1.z) | ((uint32_t)f32_to_bf16_rne(f1.w) << 16);
            *(uint4*)&As[row * LSTR + ko] = v;
        }
        // stage B^T tile: 128 n-rows x 32 k (already bf16)
        #pragma unroll
        for (int c = tid; c < 512; c += 256) {
            int row = c >> 2;
            int ko  = (c & 3) << 3;
            uint4 val = *(const uint4*)(wtb + (size_t)row * K_DIM + k0 + ko);
            *(uint4*)&Bs[row * LSTR + ko] = val;
        }
        __syncthreads();

        bf16x8 af[4], bfr[4];
        #pragma unroll
        for (int i = 0; i < 4; i++)
            af[i] = *(const bf16x8*)&As[(wm + i * 16 + lrow) * LSTR + kbase];
        #pragma unroll
        for (int j = 0; j < 4; j++)
            bfr[j] = *(const bf16x8*)&Bs[(wn + j * 16 + lrow) * LSTR + kbase];

        #pragma unroll
        for (int i = 0; i < 4; i++)
            #pragma unroll
            for (int j = 0; j < 4; j++)
                acc[i][j] = __builtin_amdgcn_mfma_f32_16x16x32_bf16(
                                af[i], bfr[j], acc[i][j], 0, 0, 0);
        __syncthreads();
    }

    // epilogue: D row=(lane>>4)*4+r, col=lane&15
    const int quad  = lane >> 4;
    const int nbase = wsel * H_DIM + wn;
    #pragma unroll
    for (int i = 0; i < 4; i++) {
        #pragma unroll
        for (int j = 0; j < 4; j++) {
            #pragma unroll
            for (int r = 0; r < 4; r++) {
                int grow = m0 + wm + i * 16 + quad * 4 + r;
                int gcol = nbase + j * 16 + lrow;
                qkv[(size_t)grow * NQ + gcol] = acc[i][j][r];
            }
        }
    }
}

// ---------------------------------------------------------------------------
// Kernel 3: per-row rank-1 softmax attention
// out[b][i] = sum_j softmax_j(q_i * k_j / sqrt(K)) * v_j
// block = 256 threads = 2 batch rows x 128 head elems. fp32 in, fp32 out.
// ---------------------------------------------------------------------------
#define SCALE 0.02525381361380526f      // 1/sqrt(1568)
#define LOG2E 1.4426950408889634f

__global__ __launch_bounds__(256) void attn_kernel(
    const float* __restrict__ qkv, float* __restrict__ out)
{
    __shared__ float kc[2][128];
    __shared__ float vv[2][128];
    __shared__ float wred[4][2];

    const int rb = threadIdx.x >> 7;        // which of 2 rows
    const int i  = threadIdx.x & 127;
    const size_t b = (size_t)blockIdx.x * 2 + rb;
    const float* base = qkv + b * NQ;

    float qq  = base[i] * (SCALE * LOG2E);  // fold scale + log2e into q
    float kvl = base[128 + i];
    float vvl = base[256 + i];
    kc[rb][i] = kvl;
    vv[rb][i] = vvl;

    // wave-level max/min of k over 64 lanes, then combine two waves via LDS
    float mx = kvl, mn = kvl;
    #pragma unroll
    for (int off = 32; off >= 1; off >>= 1) {
        mx = fmaxf(mx, __shfl_xor(mx, off));
        mn = fminf(mn, __shfl_xor(mn, off));
    }
    const int wave = threadIdx.x >> 6;
    if ((threadIdx.x & 63) == 0) { wred[wave][0] = mx; wred[wave][1] = mn; }
    __syncthreads();

    float rmx = fmaxf(wred[rb * 2][0], wred[rb * 2 + 1][0]);
    float rmn = fminf(wred[rb * 2][1], wred[rb * 2 + 1][1]);
    float mi  = (qq >= 0.f) ? qq * rmx : qq * rmn;   // max_j of qq*k_j

    float num = 0.f, den = 0.f;
    #pragma unroll 8
    for (int j = 0; j < 128; ++j) {
        float e = __builtin_amdgcn_exp2f(qq * kc[rb][j] - mi);
        den += e;
        num += e * vv[rb][j];
    }
    out[b * H_DIM + i] = num / den;
}

// ---------------------------------------------------------------------------
extern "C" void kernel_launch(void* const* d_in, const int* in_sizes, int n_in,
                              void* d_out, int out_size, void* d_ws, size_t ws_size,
                              hipStream_t stream)
{
    const float* x  = (const float*)d_in[0];
    const float* wq = (const float*)d_in[1];
    const float* wk = (const float*)d_in[2];
    const float* wv = (const float*)d_in[3];
    float* out = (float*)d_out;

    // workspace layout: WT bf16 [3][128][1568] (1204224 B, 16-aligned), then qkv fp32
    u16*   wt  = (u16*)d_ws;
    float* qkv = (float*)((char*)d_ws + (size_t)3 * H_DIM * K_DIM * 2);

    wtrans_kernel<<<dim3((H_DIM * K_DIM) / 256, 3), 256, 0, stream>>>(wq, wk, wv, wt);
    qkv_gemm_kernel<<<dim3(M_ROWS / 128, 3), 256, 0, stream>>>(x, wt, qkv);
    attn_kernel<<<M_ROWS / 2, 256, 0, stream>>>(qkv, out);
}

// Round 3
// 254.777 us; speedup vs baseline: 1.0867x; 1.0867x over previous
//
#include <hip/hip_runtime.h>
#include <stdint.h>

typedef unsigned short u16;
typedef __bf16 bf16x8 __attribute__((ext_vector_type(8)));
typedef float f32x4 __attribute__((ext_vector_type(4)));

#define M_ROWS 16384
#define K_DIM  1568
#define H_DIM  128
#define MT     32            // M rows per block
#define PSTR   132           // LDS row stride in f32 (128 + 4 pad -> conflict-free)
#define SCALE  0.02525381361380526f   // 1/sqrt(1568)
#define LOG2E  1.4426950408889634f

__device__ __forceinline__ u16 f32_to_bf16_rne(float f) {
    uint32_t u = __float_as_uint(f);
    uint32_t r = (u + 0x7FFFu + ((u >> 16) & 1u)) >> 16;
    return (u16)r;
}

__device__ __forceinline__ bf16x8 cvt8(float4 f0, float4 f1) {
    union { uint32_t u[4]; bf16x8 v; } p;
    p.u[0] = (uint32_t)f32_to_bf16_rne(f0.x) | ((uint32_t)f32_to_bf16_rne(f0.y) << 16);
    p.u[1] = (uint32_t)f32_to_bf16_rne(f0.z) | ((uint32_t)f32_to_bf16_rne(f0.w) << 16);
    p.u[2] = (uint32_t)f32_to_bf16_rne(f1.x) | ((uint32_t)f32_to_bf16_rne(f1.y) << 16);
    p.u[3] = (uint32_t)f32_to_bf16_rne(f1.z) | ((uint32_t)f32_to_bf16_rne(f1.w) << 16);
    return p.v;
}

// ---------------------------------------------------------------------------
// Kernel 1: transpose + bf16-convert [K,H] f32 weights -> WT[3][H][K] bf16
// ---------------------------------------------------------------------------
__global__ __launch_bounds__(256) void wtrans_kernel(
    const float* __restrict__ wq, const float* __restrict__ wk,
    const float* __restrict__ wv, u16* __restrict__ wt)
{
    const float* w = (blockIdx.y == 0) ? wq : (blockIdx.y == 1) ? wk : wv;
    int idx = blockIdx.x * 256 + threadIdx.x;      // over H*K = 200704 (exact)
    int n = idx / K_DIM;
    int k = idx - n * K_DIM;
    wt[(size_t)blockIdx.y * H_DIM * K_DIM + idx] =
        f32_to_bf16_rne(w[(size_t)k * H_DIM + n]);
}

// ---------------------------------------------------------------------------
// Kernel 2 (fused): per block of 32 batch rows:
//   phase 1: [q|k|v][32][128] = x[32][K] @ WT^T  via barrier-free MFMA,
//            fragments loaded directly from global (no LDS staging)
//   phase 2: rank-1 softmax attention entirely in LDS/registers
// block = 256 threads = 4 waves; wave w owns n-range [w*96, w*96+96)
// ---------------------------------------------------------------------------
__global__ __launch_bounds__(256, 2) void fused_kernel(
    const float* __restrict__ x,     // [M,K] fp32
    const u16* __restrict__ wt,      // [3][H][K] bf16 bits
    float* __restrict__ out)         // [M,H] fp32
{
    __shared__ float P[3][MT][PSTR];   // q / k / v, padded rows

    const int tid  = threadIdx.x;
    const int lane = tid & 63;
    const int wave = tid >> 6;
    const int lrow = lane & 15;
    const int quad = lane >> 4;
    const int m0   = blockIdx.x * MT;

    // ---------------- GEMM phase ----------------
    f32x4 acc[2][6] = {};
    const int n0 = wave * 96;

    const u16* bptr[6];
    #pragma unroll
    for (int nt = 0; nt < 6; nt++) {
        int ng = n0 + nt * 16 + lrow;             // global n in [0,384)
        bptr[nt] = wt + (size_t)(ng >> 7) * (H_DIM * K_DIM)
                      + (size_t)(ng & 127) * K_DIM + quad * 8;
    }
    const float* aptr0 = x + (size_t)(m0 + lrow) * K_DIM + quad * 8;
    const float* aptr1 = aptr0 + (size_t)16 * K_DIM;

    for (int k0 = 0; k0 < K_DIM; k0 += 32) {
        bf16x8 af[2];
        {
            float4 f0 = *(const float4*)(aptr0 + k0);
            float4 f1 = *(const float4*)(aptr0 + k0 + 4);
            af[0] = cvt8(f0, f1);
            float4 g0 = *(const float4*)(aptr1 + k0);
            float4 g1 = *(const float4*)(aptr1 + k0 + 4);
            af[1] = cvt8(g0, g1);
        }
        #pragma unroll
        for (int nt = 0; nt < 6; nt++) {
            bf16x8 bf = *(const bf16x8*)(bptr[nt] + k0);
            acc[0][nt] = __builtin_amdgcn_mfma_f32_16x16x32_bf16(af[0], bf, acc[0][nt], 0, 0, 0);
            acc[1][nt] = __builtin_amdgcn_mfma_f32_16x16x32_bf16(af[1], bf, acc[1][nt], 0, 0, 0);
        }
    }

    // scatter accumulators to LDS: D row=(quad*4+r), col=lrow
    #pragma unroll
    for (int mt = 0; mt < 2; mt++) {
        #pragma unroll
        for (int nt = 0; nt < 6; nt++) {
            int ng  = n0 + nt * 16 + lrow;
            int sel = ng >> 7;
            int col = ng & 127;
            int mrow = mt * 16 + quad * 4;
            #pragma unroll
            for (int r = 0; r < 4; r++)
                P[sel][mrow + r][col] = acc[mt][nt][r];
        }
    }
    __syncthreads();

    // ---------------- attention phase ----------------
    // thread -> (row r = tid>>3, sub = tid&7); 16 output elems per thread
    const int r   = tid >> 3;
    const int sub = tid & 7;

    // per-row kmax / kmin (rank-1 trick: max_j q*k_j = q>=0 ? q*kmax : q*kmin)
    float kmx = -1e30f, kmn = 1e30f;
    #pragma unroll
    for (int jj = 0; jj < 16; jj++) {
        float kv = P[1][r][sub * 16 + jj];
        kmx = fmaxf(kmx, kv);
        kmn = fminf(kmn, kv);
    }
    #pragma unroll
    for (int off = 1; off <= 4; off <<= 1) {
        kmx = fmaxf(kmx, __shfl_xor(kmx, off));
        kmn = fminf(kmn, __shfl_xor(kmn, off));
    }

    float qq[16], mi[16], num[16], den[16];
    #pragma unroll
    for (int ii = 0; ii < 16; ii++) {
        float q = P[0][r][sub * 16 + ii] * (SCALE * LOG2E);
        qq[ii]  = q;
        mi[ii]  = (q >= 0.f) ? q * kmx : q * kmn;
        num[ii] = 0.f;
        den[ii] = 0.f;
    }

    #pragma unroll 2
    for (int j = 0; j < 128; j++) {
        float kj = P[1][r][j];
        float vj = P[2][r][j];
        #pragma unroll
        for (int ii = 0; ii < 16; ii++) {
            float e = __builtin_amdgcn_exp2f(qq[ii] * kj - mi[ii]);
            den[ii] += e;
            num[ii] += e * vj;
        }
    }

    float* op = out + (size_t)(m0 + r) * H_DIM + sub * 16;
    #pragma unroll
    for (int g = 0; g < 4; g++) {
        float4 o;
        o.x = num[4 * g + 0] / den[4 * g + 0];
        o.y = num[4 * g + 1] / den[4 * g + 1];
        o.z = num[4 * g + 2] / den[4 * g + 2];
        o.w = num[4 * g + 3] / den[4 * g + 3];
        *(float4*)(op + 4 * g) = o;
    }
}

// ---------------------------------------------------------------------------
extern "C" void kernel_launch(void* const* d_in, const int* in_sizes, int n_in,
                              void* d_out, int out_size, void* d_ws, size_t ws_size,
                              hipStream_t stream)
{
    const float* x  = (const float*)d_in[0];
    const float* wq = (const float*)d_in[1];
    const float* wk = (const float*)d_in[2];
    const float* wv = (const float*)d_in[3];
    float* out = (float*)d_out;

    u16* wt = (u16*)d_ws;   // [3][128][1568] bf16 = 1.2 MB

    wtrans_kernel<<<dim3((H_DIM * K_DIM) / 256, 3), 256, 0, stream>>>(wq, wk, wv, wt);
    fused_kernel<<<M_ROWS / MT, 256, 0, stream>>>(x, wt, out);
}

// Round 4
// 240.317 us; speedup vs baseline: 1.1521x; 1.0602x over previous
//
#include <hip/hip_runtime.h>
#include <stdint.h>

typedef unsigned short u16;
typedef __bf16 bf16x8 __attribute__((ext_vector_type(8)));
typedef float f32x4 __attribute__((ext_vector_type(4)));

#define M_ROWS 16384
#define K_DIM  1568
#define H_DIM  128
#define MT     32              // batch rows per block
#define BK     32
#define NITER  49              // K_DIM / BK
#define ASTR   36              // A-tile row stride in u16 (32 + 4 pad; 72B rows, 8B aligned)
#define PSTR   132             // P row stride in f32 (128 + 4 pad)
#define SCALE  0.02525381361380526f   // 1/sqrt(1568)
#define LOG2E  1.4426950408889634f

__device__ __forceinline__ u16 f32_to_bf16_rne(float f) {
    uint32_t u = __float_as_uint(f);
    uint32_t r = (u + 0x7FFFu + ((u >> 16) & 1u)) >> 16;
    return (u16)r;
}

// ---------------------------------------------------------------------------
// Kernel 1: coalesced transpose + bf16 convert: [K,H] f32 -> WT[3][H][K] bf16
// grid (K/32, H/32, 3), block 256. LDS 32x32 tile, both sides coalesced.
// ---------------------------------------------------------------------------
__global__ __launch_bounds__(256) void wtrans_kernel(
    const float* __restrict__ wq, const float* __restrict__ wk,
    const float* __restrict__ wv, u16* __restrict__ wt)
{
    __shared__ u16 tile[32][33];
    const float* w = (blockIdx.z == 0) ? wq : (blockIdx.z == 1) ? wk : wv;
    const int k0 = blockIdx.x * 32;
    const int n0 = blockIdx.y * 32;

    const int tn = threadIdx.x & 31;
    const int tk = threadIdx.x >> 5;          // 8 k-rows per pass
    #pragma unroll
    for (int p = 0; p < 4; p++) {
        int kk = tk + p * 8;
        tile[kk][tn] = f32_to_bf16_rne(w[(size_t)(k0 + kk) * H_DIM + n0 + tn]);
    }
    __syncthreads();

    u16* dst = wt + (size_t)blockIdx.z * H_DIM * K_DIM;
    const int tk2 = threadIdx.x & 31;         // consecutive k -> coalesced store
    const int tn2 = threadIdx.x >> 5;
    #pragma unroll
    for (int p = 0; p < 4; p++) {
        int nn = tn2 + p * 8;
        dst[(size_t)(n0 + nn) * K_DIM + k0 + tk2] = tile[tk2][nn];
    }
}

// ---------------------------------------------------------------------------
// Kernel 2 (fused): block = 32 batch rows, 512 threads = 8 waves.
// GEMM: wave w owns n-range [w*48, w*48+48) of the 384-wide [q|k|v] proj.
//   A (x rows) staged f32->bf16 into double-buffered LDS, B reg-prefetched.
// Attention: rank-1 softmax, no max-subtraction (scores bounded), all f32.
// ---------------------------------------------------------------------------
__global__ __launch_bounds__(512) void fused_kernel(
    const float* __restrict__ x,     // [M,K] fp32
    const u16* __restrict__ wt,      // [3][H][K] bf16 bits
    float* __restrict__ out)         // [M,H] fp32
{
    __shared__ u16   As[2][MT * ASTR];   // 2 x 2304 B
    __shared__ float Pq[MT][PSTR];       // 16.9 KB (holds q * SCALE * LOG2E)
    __shared__ float Pk[MT][PSTR];
    __shared__ float Pv[MT][PSTR];

    const int tid  = threadIdx.x;
    const int lane = tid & 63;
    const int wave = tid >> 6;
    const int lrow = lane & 15;
    const int quad = lane >> 4;
    const int m0   = blockIdx.x * MT;

    // ---- staging geometry: thread loads 2 f32 of x per iter ----
    const int srow = tid >> 4;               // 32 rows
    const int scol = tid & 15;               // 16 x 2 f32 = 32 k
    const float* aptr = x + (size_t)(m0 + srow) * K_DIM + scol * 2;

    // ---- B fragment pointers (per wave, 3 n-tiles of 16) ----
    const u16* bp[3];
    #pragma unroll
    for (int nt = 0; nt < 3; nt++) {
        int ng = wave * 48 + nt * 16 + lrow;
        bp[nt] = wt + (size_t)(ng >> 7) * (H_DIM * K_DIM)
                    + (size_t)(ng & 127) * K_DIM + quad * 8;
    }

    // ---- prologue: stage k=0, load B(k=0) ----
    {
        float2 a0 = *(const float2*)(aptr);
        uint32_t p = (uint32_t)f32_to_bf16_rne(a0.x)
                   | ((uint32_t)f32_to_bf16_rne(a0.y) << 16);
        ((uint32_t*)&As[0][srow * ASTR])[scol] = p;
    }
    bf16x8 bcur[3];
    #pragma unroll
    for (int nt = 0; nt < 3; nt++) bcur[nt] = *(const bf16x8*)(bp[nt]);
    __syncthreads();

    f32x4 acc[2][3] = {};

    for (int kk = 0; kk < NITER; kk++) {
        const int kn = (kk < NITER - 1) ? (kk + 1) * BK : kk * BK;  // clamped
        // issue next-iter global loads first (prefetch)
        float2 an = *(const float2*)(aptr + kn);
        bf16x8 bn0 = *(const bf16x8*)(bp[0] + kn);
        bf16x8 bn1 = *(const bf16x8*)(bp[1] + kn);
        bf16x8 bn2 = *(const bf16x8*)(bp[2] + kn);

        // A fragments from LDS (current buffer)
        const int buf = kk & 1;
        union { uint2 h[2]; bf16x8 v; } a0f, a1f;
        {
            const u16* ap0 = &As[buf][(0 * 16 + lrow) * ASTR + quad * 8];
            const u16* ap1 = &As[buf][(1 * 16 + lrow) * ASTR + quad * 8];
            a0f.h[0] = *(const uint2*)(ap0);
            a0f.h[1] = *(const uint2*)(ap0 + 4);
            a1f.h[0] = *(const uint2*)(ap1);
            a1f.h[1] = *(const uint2*)(ap1 + 4);
        }

        acc[0][0] = __builtin_amdgcn_mfma_f32_16x16x32_bf16(a0f.v, bcur[0], acc[0][0], 0, 0, 0);
        acc[1][0] = __builtin_amdgcn_mfma_f32_16x16x32_bf16(a1f.v, bcur[0], acc[1][0], 0, 0, 0);
        acc[0][1] = __builtin_amdgcn_mfma_f32_16x16x32_bf16(a0f.v, bcur[1], acc[0][1], 0, 0, 0);
        acc[1][1] = __builtin_amdgcn_mfma_f32_16x16x32_bf16(a1f.v, bcur[1], acc[1][1], 0, 0, 0);
        acc[0][2] = __builtin_amdgcn_mfma_f32_16x16x32_bf16(a0f.v, bcur[2], acc[0][2], 0, 0, 0);
        acc[1][2] = __builtin_amdgcn_mfma_f32_16x16x32_bf16(a1f.v, bcur[2], acc[1][2], 0, 0, 0);

        // convert + store next A tile into the other buffer
        {
            uint32_t p = (uint32_t)f32_to_bf16_rne(an.x)
                       | ((uint32_t)f32_to_bf16_rne(an.y) << 16);
            ((uint32_t*)&As[buf ^ 1][srow * ASTR])[scol] = p;
        }
        __syncthreads();
        bcur[0] = bn0; bcur[1] = bn1; bcur[2] = bn2;
    }

    // ---- scatter projections to LDS (D: row = quad*4+r, col = lane&15) ----
    #pragma unroll
    for (int mt = 0; mt < 2; mt++) {
        #pragma unroll
        for (int nt = 0; nt < 3; nt++) {
            const int base = wave * 48 + nt * 16;    // tile never straddles heads
            const int sel  = base >> 7;
            const int col  = (base & 127) + lrow;
            const int mrow = mt * 16 + quad * 4;
            if (sel == 0) {
                #pragma unroll
                for (int r = 0; r < 4; r++)
                    Pq[mrow + r][col] = acc[mt][nt][r] * (SCALE * LOG2E);
            } else if (sel == 1) {
                #pragma unroll
                for (int r = 0; r < 4; r++)
                    Pk[mrow + r][col] = acc[mt][nt][r];
            } else {
                #pragma unroll
                for (int r = 0; r < 4; r++)
                    Pv[mrow + r][col] = acc[mt][nt][r];
            }
        }
    }
    __syncthreads();

    // ---- attention: r = row, 16 subs x 8 outputs ----
    const int r   = tid >> 4;
    const int sub = tid & 15;

    float qq[8], num[8], den[8];
    #pragma unroll
    for (int ii = 0; ii < 8; ii++) {
        qq[ii]  = Pq[r][sub * 8 + ii];
        num[ii] = 0.f;
        den[ii] = 0.f;
    }

    #pragma unroll 4
    for (int j = 0; j < 128; j++) {
        float kj = Pk[r][j];
        float vj = Pv[r][j];
        #pragma unroll
        for (int ii = 0; ii < 8; ii++) {
            float e = __builtin_amdgcn_exp2f(qq[ii] * kj);
            den[ii] += e;
            num[ii] += e * vj;
        }
    }

    float* op = out + (size_t)(m0 + r) * H_DIM + sub * 8;
    #pragma unroll
    for (int g = 0; g < 2; g++) {
        float4 o;
        o.x = num[4 * g + 0] / den[4 * g + 0];
        o.y = num[4 * g + 1] / den[4 * g + 1];
        o.z = num[4 * g + 2] / den[4 * g + 2];
        o.w = num[4 * g + 3] / den[4 * g + 3];
        *(float4*)(op + 4 * g) = o;
    }
}

// ---------------------------------------------------------------------------
extern "C" void kernel_launch(void* const* d_in, const int* in_sizes, int n_in,
                              void* d_out, int out_size, void* d_ws, size_t ws_size,
                              hipStream_t stream)
{
    const float* x  = (const float*)d_in[0];
    const float* wq = (const float*)d_in[1];
    const float* wk = (const float*)d_in[2];
    const float* wv = (const float*)d_in[3];
    float* out = (float*)d_out;

    u16* wt = (u16*)d_ws;   // [3][128][1568] bf16 = 1.2 MB

    wtrans_kernel<<<dim3(K_DIM / 32, H_DIM / 32, 3), 256, 0, stream>>>(wq, wk, wv, wt);
    fused_kernel<<<M_ROWS / MT, 512, 0, stream>>>(x, wt, out);
}